// Round 11
// baseline (46.940 us; speedup 1.0000x reference)
//
#include <hip/hip_runtime.h>
#include <hip/hip_cooperative_groups.h>
#include <math.h>

namespace cg = cooperative_groups;

#define NROWS 8192
#define DIN   256
#define NH    8
#define NC    128
#define DOUT  256

typedef unsigned short ushort_t;
typedef __attribute__((ext_vector_type(8))) short bf16x8;
typedef __attribute__((ext_vector_type(4))) float f32x4;
typedef __attribute__((ext_vector_type(8))) unsigned short u16x8;

static __device__ __forceinline__ ushort_t f2bf(float f) {
  union { float f; unsigned u; } v; v.f = f;
  unsigned r = v.u + 0x7fffu + ((v.u >> 16) & 1u);
  return (ushort_t)(r >> 16);
}
static __device__ __forceinline__ float bf2f(ushort_t h) {
  union { unsigned u; float f; } v; v.u = ((unsigned)h) << 16;
  return v.f;
}

#define MFMA16(a, b, c) __builtin_amdgcn_mfma_f32_16x16x32_bf16((a), (b), (c), 0, 0, 0)
#define GLOAD_LDS16(g, l)                                                     \
  __builtin_amdgcn_global_load_lds(                                           \
      (const __attribute__((address_space(1))) void*)(g),                     \
      (__attribute__((address_space(3))) void*)(l), 16, 0, 0)

// ---------------------------------------------------------------------------
// prep unit (bid in [0,1536)) — body identical to r9 prep_kernel
// ---------------------------------------------------------------------------
static __device__ __forceinline__ void prep_unit(
    int bid, int t, const float* Wq, const float* ctrs, const float* Wo,
    const float* Wv, const float* Ov, ushort_t* wcvtT, ushort_t* ctr3T,
    float* cbias, ushort_t* WoT, ushort_t* W2bT) {
  if (bid < 512) {
    int j = bid, k = t;
    int h = j >> 6, p = j & 63;
    float v = Wq[((size_t)k * 64 + p) * 8 + h];
    ushort_t hi = f2bf(v), lo = f2bf(v - bf2f(hi));
    wcvtT[(size_t)j * 512 + k]       = hi;
    wcvtT[(size_t)j * 512 + 256 + k] = lo;
  } else if (bid < 768) {
    int idx = (bid - 512) * 4 + (t >> 6);   // h*128+c
    int p = t & 63;
    float v = ctrs[(size_t)idx * 64 + p];
    float sq = v * v;
    #pragma unroll
    for (int off = 32; off >= 1; off >>= 1) sq += __shfl_xor(sq, off, 64);
    if (p == 0) cbias[idx] = -sq;
    ushort_t hi = f2bf(v), lo = f2bf(v - bf2f(hi));
    ctr3T[(size_t)idx * 192 + p]       = hi;
    ctr3T[(size_t)idx * 192 + 64 + p]  = lo;
    ctr3T[(size_t)idx * 192 + 128 + p] = hi;
  } else if (bid < 1280) {
    int k = bid - 768;    // 0..511
    int n = t;            // 0..255
    WoT[(size_t)n * 512 + k] = f2bf(Wo[(size_t)k * 256 + n]);
  } else {
    int b = (bid - 1280) * 4 + (t >> 6);   // h*128 + c
    int p = t & 63;
    int h = b >> 7, c = b & 127;
    const float* wv = Wv + (size_t)b * 4096;
    float acc = 0.f;
    #pragma unroll 8
    for (int g = 0; g < 64; ++g) acc += wv[g * 64 + p];
    W2bT[((size_t)h * 128 + p) * 128 + c]      = f2bf(acc);
    W2bT[((size_t)h * 128 + 64 + p) * 128 + c] = f2bf(Ov[(size_t)b * 64 + p]);
  }
}

// ---------------------------------------------------------------------------
// fused tile (tile in [0,1024)) — body identical to r9 fused_all_kernel,
// with LDS passed in and a benign leading drain+barrier (loop reuse).
// ---------------------------------------------------------------------------
#define STAGE_B(BUF, SRC, LDB, KOFF)                                          \
  {                                                                           \
    _Pragma("unroll")                                                         \
    for (int i = 0; i < 4; ++i) {                                             \
      int q = (i * 4 + w) * 64 + l;                                           \
      int row = q >> 3, s = q & 7;                                            \
      GLOAD_LDS16((SRC) + (size_t)(h * 128 + row) * (LDB) + (KOFF) +          \
                      ((s ^ (row & 7)) << 3),                                 \
                  (char*)(BUF) + (size_t)(i * 4 + w) * 1024);                 \
    }                                                                         \
  }

#define STAGE_BX(BUF, KC)                                                     \
  {                                                                           \
    _Pragma("unroll")                                                         \
    for (int i = 0; i < 4; ++i) {                                             \
      int q = (i * 4 + w) * 64 + l;                                           \
      int row = q >> 3, s = q & 7;                                            \
      int sw = (s ^ (row & 7)) << 3;                                          \
      int jj = h * 64 + (row & 63);                                           \
      int koff = (row < 64 ? 0 : 256) + (KC) * 64 + sw;                       \
      GLOAD_LDS16(wcvtT + (size_t)jj * 512 + koff,                            \
                  (char*)(BUF) + (size_t)(i * 4 + w) * 1024);                 \
    }                                                                         \
  }

#define MFMA_STEP(BUF, ACC, ALDS, KBASE, ASPLIT)                              \
  {                                                                           \
    _Pragma("unroll")                                                         \
    for (int kk = 0; kk < 2; ++kk) {                                          \
      int klog = (KBASE) + kk * 32 + lk * 8;                                  \
      int kp = (ASPLIT) ? (klog < 64 ? klog : klog - 64) : klog;              \
      bf16x8 af = *(const bf16x8*)&(ALDS)[(w * 16 + lr) * 136 + kp];          \
      _Pragma("unroll")                                                       \
      for (int cj = 0; cj < 8; ++cj) {                                        \
        int brow = cj * 16 + lr;                                              \
        int slot = (kk * 4 + lk) ^ (brow & 7);                                \
        bf16x8 bfr =                                                          \
            *(const bf16x8*)((const char*)(BUF) + brow * 128 + slot * 16);    \
        (ACC)[cj] = MFMA16(af, bfr, (ACC)[cj]);                               \
      }                                                                       \
    }                                                                         \
  }

#define MFMAX(BUF)                                                            \
  {                                                                           \
    _Pragma("unroll")                                                         \
    for (int kk = 0; kk < 2; ++kk) {                                          \
      bf16x8 ah = *(const bf16x8*)&Axh[(w * 16 + lr) * 72 + kk * 32 + lk * 8];\
      bf16x8 al = *(const bf16x8*)&Axl[(w * 16 + lr) * 72 + kk * 32 + lk * 8];\
      _Pragma("unroll")                                                       \
      for (int cj = 0; cj < 4; ++cj) {                                        \
        int rh = cj * 16 + lr;                                                \
        int slot = (kk * 4 + lk) ^ (rh & 7);                                  \
        bf16x8 bh = *(const bf16x8*)((const char*)(BUF) + rh * 128 + slot * 16);\
        bf16x8 bl = *(const bf16x8*)((const char*)(BUF) + (64 + rh) * 128 + slot * 16);\
        acc_x[cj] = MFMA16(ah, bh, acc_x[cj]);                                \
        acc_x[cj] = MFMA16(al, bh, acc_x[cj]);                                \
        acc_x[cj] = MFMA16(ah, bl, acc_x[cj]);                                \
      }                                                                       \
    }                                                                         \
  }

#define BAR() __builtin_amdgcn_s_barrier()
#define SCHED() __builtin_amdgcn_sched_barrier(0)
#define DRAIN_LGKM()                                                          \
  { asm volatile("s_waitcnt lgkmcnt(0)" ::: "memory"); SCHED(); }

#define LOAD_X(KC)                                                            \
  {                                                                           \
    _Pragma("unroll")                                                         \
    for (int j = 0; j < 4; ++j) xr[j] = *(const float4*)(xbase + (KC) * 64 + j * 4); \
  }

#define CVT_AX()                                                              \
  {                                                                           \
    u16x8 hv0, hv1, lv0, lv1;                                                 \
    _Pragma("unroll")                                                         \
    for (int j = 0; j < 2; ++j) {                                             \
      float f4[8] = {xr[j*2].x, xr[j*2].y, xr[j*2].z, xr[j*2].w,              \
                     xr[j*2+1].x, xr[j*2+1].y, xr[j*2+1].z, xr[j*2+1].w};     \
      _Pragma("unroll")                                                       \
      for (int e = 0; e < 8; ++e) {                                           \
        ushort_t hi = f2bf(f4[e]);                                            \
        if (j == 0) { hv0[e] = hi; lv0[e] = f2bf(f4[e] - bf2f(hi)); }         \
        else        { hv1[e] = hi; lv1[e] = f2bf(f4[e] - bf2f(hi)); }         \
      }                                                                       \
    }                                                                         \
    *(u16x8*)&Axh[xrow * 72 + xseg]     = hv0;                                \
    *(u16x8*)&Axh[xrow * 72 + xseg + 8] = hv1;                                \
    *(u16x8*)&Axl[xrow * 72 + xseg]     = lv0;                                \
    *(u16x8*)&Axl[xrow * 72 + xseg + 8] = lv1;                                \
  }

static __device__ __forceinline__ void fused_tile(
    int tile, const float* x, const ushort_t* wcvtT, const ushort_t* ctr3T,
    const float* cbias, const ushort_t* W2bT, ushort_t* ho2,
    char* Au_raw, char* B0, char* B1, float* cb_lds) {
  ushort_t* Axh = (ushort_t*)Au_raw;            // [64][72]
  ushort_t* Axl = (ushort_t*)(Au_raw + 9216);   // [64][72]
  ushort_t* A1  = (ushort_t*)Au_raw;            // [64][136] hi|lo
  ushort_t* A2  = (ushort_t*)Au_raw;            // [64][136] assignments

  const int t = threadIdx.x;
  const int w = t >> 6, l = t & 63;
  const int lr = l & 15, lk = l >> 4;
  const int h = tile >> 7;
  const int n0 = (tile & 127) * 64;
  const int xrow = t >> 2;                 // 0..63
  const int xseg = (t & 3) << 4;           // 0/16/32/48
  const float* xbase = x + (size_t)(n0 + xrow) * 256 + xseg;
  float4 xr[4];

  // boundary: any previous tile's LDS reads drained before restage
  DRAIN_LGKM(); BAR(); SCHED();

  // ---- prologue ----
  cb_lds[t & 127] = cbias[h * 128 + (t & 127)];
  LOAD_X(0);
  STAGE_BX(B0, 0);
  SCHED();                                 // pin B0 before B1 (vmcnt counting)
  STAGE_BX(B1, 1);
  SCHED();
  f32x4 acc_x[4];
  #pragma unroll
  for (int cj = 0; cj < 4; ++cj) acc_x[cj] = (f32x4){0.f, 0.f, 0.f, 0.f};
  CVT_AX();                                // consume x0
  SCHED();
  LOAD_X(1);                               // Q: [B0:4, B1:4, x1:4]
  asm volatile("s_waitcnt vmcnt(8)" ::: "memory");  // B0 done
  DRAIN_LGKM(); BAR(); SCHED();
  // chunk 0
  MFMAX(B0);
  DRAIN_LGKM(); BAR(); SCHED();
  STAGE_BX(B0, 2);                         // Q: [B1, x1, B2]
  SCHED();
  CVT_AX();                                // consume x1 -> forces B1 done
  SCHED();
  LOAD_X(2);                               // Q: [B2:4, x2:4]
  DRAIN_LGKM(); BAR(); SCHED();
  // chunk 1
  MFMAX(B1);
  DRAIN_LGKM(); BAR(); SCHED();
  STAGE_BX(B1, 3);                         // Q: [B2, x2, B3]
  SCHED();
  CVT_AX();                                // consume x2 -> forces B2 done
  SCHED();
  LOAD_X(3);                               // Q: [B3:4, x3:4]
  DRAIN_LGKM(); BAR(); SCHED();
  // chunk 2
  MFMAX(B0);
  DRAIN_LGKM(); BAR(); SCHED();
  STAGE_B(B0, ctr3T, 192, 0);              // Q: [B3, x3, ctr0]
  SCHED();
  CVT_AX();                                // consume x3 -> forces B3 done
  DRAIN_LGKM(); BAR(); SCHED();
  // chunk 3
  MFMAX(B1);
  DRAIN_LGKM(); BAR(); SCHED();            // B1, Ax free

  // write A1 (xin hi|lo) from acc_x — own wave's rows (Ax now dead)
  STAGE_B(B1, ctr3T, 192, 64);             // Q: [ctr0:4, ctr64:4]
  #pragma unroll
  for (int cj = 0; cj < 4; ++cj) {
    #pragma unroll
    for (int r = 0; r < 4; ++r) {
      int row = w * 16 + lk * 4 + r;
      int p = cj * 16 + lr;
      float v = acc_x[cj][r];
      ushort_t hi = f2bf(v);
      A1[row * 136 + p] = hi;
      A1[row * 136 + 64 + p] = f2bf(v - bf2f(hi));
    }
  }
  asm volatile("s_waitcnt vmcnt(4)" ::: "memory");  // ctr0 done
  DRAIN_LGKM(); BAR(); SCHED();

  // ---- logits: K=192 ----
  f32x4 acc[8];
  #pragma unroll
  for (int cj = 0; cj < 8; ++cj) acc[cj] = (f32x4){0.f, 0.f, 0.f, 0.f};
  MFMA_STEP(B0, acc, A1, 0, 1);            // L0
  DRAIN_LGKM(); BAR(); SCHED();
  STAGE_B(B0, ctr3T, 192, 128);            // Q: [ctr64, ctr128]
  asm volatile("s_waitcnt vmcnt(4)" ::: "memory");
  BAR(); SCHED();
  MFMA_STEP(B1, acc, A1, 64, 1);           // L1
  DRAIN_LGKM(); BAR(); SCHED();
  STAGE_B(B1, W2bT, 128, 0);               // Q: [ctr128, W2k0]
  asm volatile("s_waitcnt vmcnt(4)" ::: "memory");
  BAR(); SCHED();
  MFMA_STEP(B0, acc, A1, 128, 1);          // L2
  DRAIN_LGKM();                            // A1 reads landed

  // ---- softmax (rows within wave; A2 overwrites A1 at own-wave rows) ----
  {
    float cbv[8];
    #pragma unroll
    for (int cj = 0; cj < 8; ++cj) cbv[cj] = cb_lds[cj * 16 + lr];
    #pragma unroll
    for (int r = 0; r < 4; ++r) {
      float v[8];
      float m = -1e30f;
      #pragma unroll
      for (int cj = 0; cj < 8; ++cj) {
        v[cj] = 2.f * acc[cj][r] + cbv[cj];
        m = fmaxf(m, v[cj]);
      }
      m = fmaxf(m, __shfl_xor(m, 1, 64));
      m = fmaxf(m, __shfl_xor(m, 2, 64));
      m = fmaxf(m, __shfl_xor(m, 4, 64));
      m = fmaxf(m, __shfl_xor(m, 8, 64));
      float s = 0.f;
      #pragma unroll
      for (int cj = 0; cj < 8; ++cj) {
        v[cj] = __expf(v[cj] - m);
        s += v[cj];
      }
      s += __shfl_xor(s, 1, 64);
      s += __shfl_xor(s, 2, 64);
      s += __shfl_xor(s, 4, 64);
      s += __shfl_xor(s, 8, 64);
      float inv = 1.f / s;
      int row = w * 16 + lk * 4 + r;
      #pragma unroll
      for (int cj = 0; cj < 8; ++cj)
        A2[row * 136 + cj * 16 + lr] = f2bf(v[cj] * inv);
    }
  }
  DRAIN_LGKM();
  BAR(); SCHED();        // safe to overwrite B0

  f32x4 accT[8];
  #pragma unroll
  for (int cj = 0; cj < 8; ++cj) accT[cj] = (f32x4){0.f, 0.f, 0.f, 0.f};
  STAGE_B(B0, W2bT, 128, 64);              // Q: [W2k0, W2k64]
  asm volatile("s_waitcnt vmcnt(4)" ::: "memory");
  BAR(); SCHED();
  MFMA_STEP(B1, accT, A2, 0, 0);           // T0
  DRAIN_LGKM();
  asm volatile("s_waitcnt vmcnt(0)" ::: "memory");
  BAR(); SCHED();
  MFMA_STEP(B0, accT, A2, 64, 0);          // T1

  // ---- epilogue: ho = xin(f32 regs)*t1 + t2 ; bounce via B1 ----
  #pragma unroll
  for (int cj = 0; cj < 4; ++cj) {
    #pragma unroll
    for (int r = 0; r < 4; ++r) {
      int row = w * 16 + lk * 4 + r;
      int p = cj * 16 + lr;
      float hov = acc_x[cj][r] * accT[cj][r] + accT[cj + 4][r];
      ((ushort_t*)B1)[row * 64 + p] = f2bf(hov);
    }
  }
  DRAIN_LGKM(); BAR(); SCHED();
  #pragma unroll
  for (int i = 0; i < 2; ++i) {
    int q = i * 256 + t;
    int row = q >> 3, s = q & 7;
    uint4 v = *(const uint4*)((const char*)B1 + row * 128 + s * 16);
    *(uint4*)(ho2 + ((size_t)h * NROWS + n0 + row) * 64 + s * 8) = v;
  }
}

// ---------------------------------------------------------------------------
// gemm2 tile (g in [0,512)): out[m0:m0+64][n0:n0+64] — body per r9 gemm2.
// ---------------------------------------------------------------------------
static __device__ __forceinline__ void gemm2_tile(
    int g, const ushort_t* ho2, const ushort_t* WoT, float* out,
    char* At, char* Bl) {
  const int t = threadIdx.x;
  const int w = t >> 6, l = t & 63;
  const int wr = w >> 1, wc = w & 1;
  const int m0 = (g >> 2) * 64, n0 = (g & 3) * 64;
  const int lr = l & 15, lk = l >> 4;

  f32x4 acc[2][2];
  #pragma unroll
  for (int a = 0; a < 2; ++a)
    #pragma unroll
    for (int b = 0; b < 2; ++b) acc[a][b] = (f32x4){0.f, 0.f, 0.f, 0.f};

  for (int k0 = 0; k0 < 512; k0 += 64) {
    #pragma unroll
    for (int i = 0; i < 2; ++i) {
      int q = (i * 4 + w) * 64 + l;
      int row = q >> 3, s = q & 7;
      int kl = k0 + ((s ^ (row & 7)) << 3);
      GLOAD_LDS16(ho2 + (size_t)(m0 + row) * 512 + kl,
                  At + (size_t)(i * 4 + w) * 1024);
    }
    #pragma unroll
    for (int i = 0; i < 2; ++i) {
      int q = (i * 4 + w) * 64 + l;
      int row = q >> 3, s = q & 7;
      int kl = k0 + ((s ^ (row & 7)) << 3);
      GLOAD_LDS16(WoT + (size_t)(n0 + row) * 512 + kl,
                  Bl + (size_t)(i * 4 + w) * 1024);
    }
    __syncthreads();
    #pragma unroll
    for (int kk = 0; kk < 2; ++kk) {
      bf16x8 af[2], bfr[2];
      #pragma unroll
      for (int a = 0; a < 2; ++a) {
        int row = wr * 32 + a * 16 + lr;
        int s = (kk * 4 + lk) ^ (row & 7);
        af[a] = *(const bf16x8*)(At + row * 128 + s * 16);
      }
      #pragma unroll
      for (int b = 0; b < 2; ++b) {
        int row = wc * 32 + b * 16 + lr;
        int s = (kk * 4 + lk) ^ (row & 7);
        bfr[b] = *(const bf16x8*)(Bl + row * 128 + s * 16);
      }
      #pragma unroll
      for (int a = 0; a < 2; ++a)
        #pragma unroll
        for (int b = 0; b < 2; ++b)
          acc[a][b] = MFMA16(af[a], bfr[b], acc[a][b]);
    }
    __syncthreads();
  }
  #pragma unroll
  for (int a = 0; a < 2; ++a) {
    #pragma unroll
    for (int b = 0; b < 2; ++b) {
      #pragma unroll
      for (int r = 0; r < 4; ++r) {
        int rowg = m0 + wr * 32 + a * 16 + lk * 4 + r;
        int colg = n0 + wc * 32 + b * 16 + lr;
        out[(size_t)rowg * 256 + colg] = acc[a][b][r];
      }
    }
  }
}

// ---------------------------------------------------------------------------
// Standalone kernels (r9-proven path)
// ---------------------------------------------------------------------------
__global__ __launch_bounds__(256) void prep_kernel(
    const float* __restrict__ Wq, const float* __restrict__ ctrs,
    const float* __restrict__ Wo, const float* __restrict__ Wv,
    const float* __restrict__ Ov, ushort_t* __restrict__ wcvtT,
    ushort_t* __restrict__ ctr3T, float* __restrict__ cbias,
    ushort_t* __restrict__ WoT, ushort_t* __restrict__ W2bT) {
  prep_unit(blockIdx.x, threadIdx.x, Wq, ctrs, Wo, Wv, Ov, wcvtT, ctr3T,
            cbias, WoT, W2bT);
}

__global__ __launch_bounds__(256, 3) void fused_all_kernel(
    const float* __restrict__ x, const ushort_t* __restrict__ wcvtT,
    const ushort_t* __restrict__ ctr3T, const float* __restrict__ cbias,
    const ushort_t* __restrict__ W2bT, ushort_t* __restrict__ ho2) {
  __shared__ __align__(16) char Au_raw[18432];
  __shared__ char B0[16384];
  __shared__ char B1[16384];
  __shared__ float cb_lds[128];
  fused_tile(blockIdx.x, x, wcvtT, ctr3T, cbias, W2bT, ho2,
             Au_raw, B0, B1, cb_lds);
}

__global__ __launch_bounds__(256) void gemm2_kernel(
    const ushort_t* __restrict__ ho2, const ushort_t* __restrict__ WoT,
    float* __restrict__ out) {
  __shared__ char At[8192];
  __shared__ char Bl[8192];
  gemm2_tile(blockIdx.x, ho2, WoT, out, At, Bl);
}

// ---------------------------------------------------------------------------
// Cooperative mono kernel — grid-stride phases; valid for ANY grid size.
// ---------------------------------------------------------------------------
__global__ __launch_bounds__(256, 2) void mono_kernel(
    const float* __restrict__ x, const float* __restrict__ ctrs,
    const float* __restrict__ Wv, const float* __restrict__ Ov,
    const float* __restrict__ Wq, const float* __restrict__ Wo,
    ushort_t* __restrict__ wcvtT, ushort_t* __restrict__ ctr3T,
    float* __restrict__ cbias, ushort_t* __restrict__ WoT,
    ushort_t* __restrict__ W2bT, ushort_t* __restrict__ ho2,
    float* __restrict__ out) {
  __shared__ __align__(16) char Au_raw[18432];
  __shared__ char B0[16384];
  __shared__ char B1[16384];
  __shared__ float cb_lds[128];

  const unsigned b0 = blockIdx.x;
  const unsigned g = gridDim.x;
  const int t = threadIdx.x;

  for (unsigned bid = b0; bid < 1536; bid += g)
    prep_unit((int)bid, t, Wq, ctrs, Wo, Wv, Ov, wcvtT, ctr3T, cbias, WoT, W2bT);
  cg::this_grid().sync();

  for (unsigned tile = b0; tile < 1024; tile += g)
    fused_tile((int)tile, x, wcvtT, ctr3T, cbias, W2bT, ho2,
               Au_raw, B0, B1, cb_lds);
  cg::this_grid().sync();

  for (unsigned gg = b0; gg < 512; gg += g)
    gemm2_tile((int)gg, ho2, WoT, out, B0, B1);
}

#undef STAGE_B
#undef STAGE_BX
#undef MFMA_STEP
#undef MFMAX
#undef BAR
#undef SCHED
#undef DRAIN_LGKM
#undef LOAD_X
#undef CVT_AX

// ---------------------------------------------------------------------------
extern "C" void kernel_launch(void* const* d_in, const int* in_sizes, int n_in,
                              void* d_out, int out_size, void* d_ws, size_t ws_size,
                              hipStream_t stream) {
  (void)in_sizes; (void)n_in; (void)out_size; (void)ws_size;
  const float* x    = (const float*)d_in[0];
  const float* ctrs = (const float*)d_in[1];
  const float* Wv   = (const float*)d_in[2];
  const float* Ov   = (const float*)d_in[3];
  const float* Wq   = (const float*)d_in[4];
  const float* Wo   = (const float*)d_in[5];
  float* out = (float*)d_out;

  char* wsb = (char*)d_ws;
  ushort_t* wcvtT = (ushort_t*)wsb;                   // [0, 524288)
  ushort_t* ctr3T = (ushort_t*)(wsb + 524288);        // [524288, 917504)
  float*    cb    = (float*)   (wsb + 917504);        // [917504, 921600)
  ushort_t* W2bT  = (ushort_t*)(wsb + 921600);        // [921600, 1183744)
  ushort_t* WoT   = (ushort_t*)(wsb + 1183744);       // [1183744, 1445888)
  ushort_t* ho2   = (ushort_t*)(wsb + 2097152);       // [2 MiB, 2 MiB + 8 MiB)

  // Query-gated decision (pure queries; capture-safe; deterministic).
  int dev = 0;
  (void)hipGetDevice(&dev);
  int coop = 0;
  (void)hipDeviceGetAttribute(&coop, hipDeviceAttributeCooperativeLaunch, dev);
  int ncu = 0;
  (void)hipDeviceGetAttribute(&ncu, hipDeviceAttributeMultiprocessorCount, dev);
  int nb = 0;
  hipError_t oe =
      hipOccupancyMaxActiveBlocksPerMultiprocessor(&nb, (const void*)mono_kernel, 256, 0);
  long cap = (oe == hipSuccess && ncu > 0 && nb > 0) ? (long)nb * (long)ncu : 0;

  if (coop != 0 && cap >= 512) {
    unsigned grid = (unsigned)(cap < 512 ? cap : 512);
    void* kargs[] = {(void*)&x,     (void*)&ctrs,  (void*)&Wv,   (void*)&Ov,
                     (void*)&Wq,    (void*)&Wo,    (void*)&wcvtT, (void*)&ctr3T,
                     (void*)&cb,    (void*)&WoT,   (void*)&W2bT, (void*)&ho2,
                     (void*)&out};
    (void)hipLaunchCooperativeKernel((const void*)mono_kernel, dim3(grid),
                                     dim3(256), kargs, 0, stream);
    return;
  }

  // Proven r9 three-kernel path.
  prep_kernel<<<1536, 256, 0, stream>>>(Wq, ctrs, Wo, Wv, Ov,
                                        wcvtT, ctr3T, cb, WoT, W2bT);
  fused_all_kernel<<<NH * 128, 256, 0, stream>>>(x, wcvtT, ctr3T, cb, W2bT, ho2);
  gemm2_kernel<<<dim3(512), 256, 0, stream>>>(ho2, WoT, out);
}

// Round 12
// 43.332 us; speedup vs baseline: 1.0833x; 1.0833x over previous
//
#include <hip/hip_runtime.h>
#include <math.h>

#define NROWS 8192
#define DIN   256
#define NH    8
#define NC    128
#define DOUT  256

typedef unsigned short ushort_t;
typedef __attribute__((ext_vector_type(8))) short bf16x8;
typedef __attribute__((ext_vector_type(4))) float f32x4;
typedef __attribute__((ext_vector_type(8))) unsigned short u16x8;

static __device__ __forceinline__ ushort_t f2bf(float f) {
  union { float f; unsigned u; } v; v.f = f;
  unsigned r = v.u + 0x7fffu + ((v.u >> 16) & 1u);
  return (ushort_t)(r >> 16);
}
static __device__ __forceinline__ float bf2f(ushort_t h) {
  union { unsigned u; float f; } v; v.u = ((unsigned)h) << 16;
  return v.f;
}

#define MFMA16(a, b, c) __builtin_amdgcn_mfma_f32_16x16x32_bf16((a), (b), (c), 0, 0, 0)
#define GLOAD_LDS16(g, l)                                                     \
  __builtin_amdgcn_global_load_lds(                                           \
      (const __attribute__((address_space(1))) void*)(g),                     \
      (__attribute__((address_space(3))) void*)(l), 16, 0, 0)

// ---------------------------------------------------------------------------
// Merged prep (grid 1536 x 256) — byte-identical to r9.
// ---------------------------------------------------------------------------
__global__ __launch_bounds__(256) void prep_kernel(
    const float* __restrict__ Wq, const float* __restrict__ ctrs,
    const float* __restrict__ Wo, const float* __restrict__ Wv,
    const float* __restrict__ Ov, ushort_t* __restrict__ wcvtT,
    ushort_t* __restrict__ ctr3T, float* __restrict__ cbias,
    ushort_t* __restrict__ WoT, ushort_t* __restrict__ W2bT) {
  int bid = blockIdx.x;
  int t = threadIdx.x;
  if (bid < 512) {
    int j = bid, k = t;
    int h = j >> 6, p = j & 63;
    float v = Wq[((size_t)k * 64 + p) * 8 + h];
    ushort_t hi = f2bf(v), lo = f2bf(v - bf2f(hi));
    wcvtT[(size_t)j * 512 + k]       = hi;
    wcvtT[(size_t)j * 512 + 256 + k] = lo;
  } else if (bid < 768) {
    int idx = (bid - 512) * 4 + (t >> 6);   // h*128+c
    int p = t & 63;
    float v = ctrs[(size_t)idx * 64 + p];
    float sq = v * v;
    #pragma unroll
    for (int off = 32; off >= 1; off >>= 1) sq += __shfl_xor(sq, off, 64);
    if (p == 0) cbias[idx] = -sq;
    ushort_t hi = f2bf(v), lo = f2bf(v - bf2f(hi));
    ctr3T[(size_t)idx * 192 + p]       = hi;
    ctr3T[(size_t)idx * 192 + 64 + p]  = lo;
    ctr3T[(size_t)idx * 192 + 128 + p] = hi;
  } else if (bid < 1280) {
    int k = bid - 768;    // 0..511
    int n = t;            // 0..255
    WoT[(size_t)n * 512 + k] = f2bf(Wo[(size_t)k * 256 + n]);
  } else {
    int b = (bid - 1280) * 4 + (t >> 6);   // h*128 + c
    int p = t & 63;
    int h = b >> 7, c = b & 127;
    const float* wv = Wv + (size_t)b * 4096;
    float acc = 0.f;
    #pragma unroll 8
    for (int g = 0; g < 64; ++g) acc += wv[g * 64 + p];
    W2bT[((size_t)h * 128 + p) * 128 + c]      = f2bf(acc);
    W2bT[((size_t)h * 128 + 64 + p) * 128 + c] = f2bf(Ov[(size_t)b * 64 + p]);
  }
}

// ---------------------------------------------------------------------------
// gemm2 — byte-identical to r9 (BM=64, 512 blocks, 2/CU).
// ---------------------------------------------------------------------------
__global__ __launch_bounds__(256) void gemm2_kernel(
    const ushort_t* __restrict__ A, const ushort_t* __restrict__ Bt,
    float* __restrict__ out) {
  __shared__ ushort_t At[64 * 64];
  __shared__ ushort_t Bl[64 * 64];
  const int t = threadIdx.x;
  const int w = t >> 6, l = t & 63;
  const int wr = w >> 1, wc = w & 1;
  const int m0 = (blockIdx.x >> 2) * 64, n0 = (blockIdx.x & 3) * 64;
  const int lr = l & 15, lk = l >> 4;

  f32x4 acc[2][2];
  #pragma unroll
  for (int a = 0; a < 2; ++a)
    #pragma unroll
    for (int b = 0; b < 2; ++b) acc[a][b] = (f32x4){0.f, 0.f, 0.f, 0.f};

  for (int k0 = 0; k0 < 512; k0 += 64) {
    #pragma unroll
    for (int i = 0; i < 2; ++i) {
      int q = (i * 4 + w) * 64 + l;
      int row = q >> 3, s = q & 7;
      int kl = k0 + ((s ^ (row & 7)) << 3);
      GLOAD_LDS16(A + (size_t)(m0 + row) * 512 + kl,
                  (char*)At + (size_t)(i * 4 + w) * 1024);
    }
    #pragma unroll
    for (int i = 0; i < 2; ++i) {
      int q = (i * 4 + w) * 64 + l;
      int row = q >> 3, s = q & 7;
      int kl = k0 + ((s ^ (row & 7)) << 3);
      GLOAD_LDS16(Bt + (size_t)(n0 + row) * 512 + kl,
                  (char*)Bl + (size_t)(i * 4 + w) * 1024);
    }
    __syncthreads();
    #pragma unroll
    for (int kk = 0; kk < 2; ++kk) {
      bf16x8 af[2], bfr[2];
      #pragma unroll
      for (int a = 0; a < 2; ++a) {
        int row = wr * 32 + a * 16 + lr;
        int s = (kk * 4 + lk) ^ (row & 7);
        af[a] = *(const bf16x8*)((const char*)At + row * 128 + s * 16);
      }
      #pragma unroll
      for (int b = 0; b < 2; ++b) {
        int row = wc * 32 + b * 16 + lr;
        int s = (kk * 4 + lk) ^ (row & 7);
        bfr[b] = *(const bf16x8*)((const char*)Bl + row * 128 + s * 16);
      }
      #pragma unroll
      for (int a = 0; a < 2; ++a)
        #pragma unroll
        for (int b = 0; b < 2; ++b)
          acc[a][b] = MFMA16(af[a], bfr[b], acc[a][b]);
    }
    __syncthreads();
  }
  #pragma unroll
  for (int a = 0; a < 2; ++a) {
    #pragma unroll
    for (int b = 0; b < 2; ++b) {
      #pragma unroll
      for (int r = 0; r < 4; ++r) {
        int rowg = m0 + wr * 32 + a * 16 + lk * 4 + r;
        int colg = n0 + wc * 32 + b * 16 + lr;
        out[(size_t)rowg * 256 + colg] = acc[a][b][r];
      }
    }
  }
}

// ---------------------------------------------------------------------------
// Fused-pair: each block = head h, 128 tokens (two 64-row A-tiles sharing
// every staged B buffer). Schedule identical to r9 fused_all; only the first
// explicit wait changes (vmcnt 8->12: x-loads are 8/thread now).
// LDS: Au union 36.9 KB (Axh/Axl[128][72] | A1/A2[128][136]) + 2x16 KB B +
// cb = 70.1 KB -> 2 blocks/CU.
// ---------------------------------------------------------------------------
__global__ __launch_bounds__(256, 2) void fused_pair_kernel(
    const float* __restrict__ x,          // [8192][256] f32
    const ushort_t* __restrict__ wcvtT,   // [512][512] hi|lo
    const ushort_t* __restrict__ ctr3T,   // [1024][192]
    const float* __restrict__ cbias,      // [1024]
    const ushort_t* __restrict__ W2bT,    // [1024][128]
    ushort_t* __restrict__ ho2) {         // flat (h,N,p)
  __shared__ __align__(16) char Au_raw[36864];
  __shared__ char B0lds[16384];
  __shared__ char B1lds[16384];
  __shared__ float cb_lds[128];

  ushort_t* Axh = (ushort_t*)Au_raw;             // [128][72]
  ushort_t* Axl = (ushort_t*)(Au_raw + 18432);   // [128][72]
  ushort_t* A1  = (ushort_t*)Au_raw;             // [128][136]
  ushort_t* A2  = (ushort_t*)Au_raw;             // [128][136]

  const int t = threadIdx.x;
  const int w = t >> 6, l = t & 63;
  const int lr = l & 15, lk = l >> 4;
  const int h = blockIdx.x >> 6;                 // 8 heads x 64 pairs
  const int n0 = (blockIdx.x & 63) * 128;

#define STAGE_B(BUF, SRC, LDB, KOFF)                                          \
  {                                                                           \
    _Pragma("unroll")                                                         \
    for (int i = 0; i < 4; ++i) {                                             \
      int q = (i * 4 + w) * 64 + l;                                           \
      int row = q >> 3, s = q & 7;                                            \
      GLOAD_LDS16((SRC) + (size_t)(h * 128 + row) * (LDB) + (KOFF) +          \
                      ((s ^ (row & 7)) << 3),                                 \
                  (char*)(BUF) + (size_t)(i * 4 + w) * 1024);                 \
    }                                                                         \
  }

#define STAGE_BX(BUF, KC)                                                     \
  {                                                                           \
    _Pragma("unroll")                                                         \
    for (int i = 0; i < 4; ++i) {                                             \
      int q = (i * 4 + w) * 64 + l;                                           \
      int row = q >> 3, s = q & 7;                                            \
      int sw = (s ^ (row & 7)) << 3;                                          \
      int jj = h * 64 + (row & 63);                                           \
      int koff = (row < 64 ? 0 : 256) + (KC) * 64 + sw;                       \
      GLOAD_LDS16(wcvtT + (size_t)jj * 512 + koff,                            \
                  (char*)(BUF) + (size_t)(i * 4 + w) * 1024);                 \
    }                                                                         \
  }

#define MFMA_STEP(BUF, ACC0, ACC1, KBASE, ASPLIT)                             \
  {                                                                           \
    _Pragma("unroll")                                                         \
    for (int kk = 0; kk < 2; ++kk) {                                          \
      int klog = (KBASE) + kk * 32 + lk * 8;                                  \
      int kp = (ASPLIT) ? (klog < 64 ? klog : klog - 64) : klog;              \
      bf16x8 af0 = *(const bf16x8*)&A1[(w * 16 + lr) * 136 + kp];             \
      bf16x8 af1 = *(const bf16x8*)&A1[(64 + w * 16 + lr) * 136 + kp];        \
      _Pragma("unroll")                                                       \
      for (int cj = 0; cj < 8; ++cj) {                                        \
        int brow = cj * 16 + lr;                                              \
        int slot = (kk * 4 + lk) ^ (brow & 7);                                \
        bf16x8 bfr =                                                          \
            *(const bf16x8*)((const char*)(BUF) + brow * 128 + slot * 16);    \
        (ACC0)[cj] = MFMA16(af0, bfr, (ACC0)[cj]);                            \
        (ACC1)[cj] = MFMA16(af1, bfr, (ACC1)[cj]);                            \
      }                                                                       \
    }                                                                         \
  }

#define MFMAX(BUF)                                                            \
  {                                                                           \
    _Pragma("unroll")                                                         \
    for (int kk = 0; kk < 2; ++kk) {                                          \
      bf16x8 ah0 = *(const bf16x8*)&Axh[(w * 16 + lr) * 72 + kk * 32 + lk * 8];     \
      bf16x8 al0 = *(const bf16x8*)&Axl[(w * 16 + lr) * 72 + kk * 32 + lk * 8];     \
      bf16x8 ah1 = *(const bf16x8*)&Axh[(64 + w * 16 + lr) * 72 + kk * 32 + lk * 8];\
      bf16x8 al1 = *(const bf16x8*)&Axl[(64 + w * 16 + lr) * 72 + kk * 32 + lk * 8];\
      _Pragma("unroll")                                                       \
      for (int cj = 0; cj < 4; ++cj) {                                        \
        int rh = cj * 16 + lr;                                                \
        int slot = (kk * 4 + lk) ^ (rh & 7);                                  \
        bf16x8 bh = *(const bf16x8*)((const char*)(BUF) + rh * 128 + slot * 16);\
        bf16x8 bl = *(const bf16x8*)((const char*)(BUF) + (64 + rh) * 128 + slot * 16);\
        acc_x0[cj] = MFMA16(ah0, bh, acc_x0[cj]);                             \
        acc_x0[cj] = MFMA16(al0, bh, acc_x0[cj]);                             \
        acc_x0[cj] = MFMA16(ah0, bl, acc_x0[cj]);                             \
        acc_x1[cj] = MFMA16(ah1, bh, acc_x1[cj]);                             \
        acc_x1[cj] = MFMA16(al1, bh, acc_x1[cj]);                             \
        acc_x1[cj] = MFMA16(ah1, bl, acc_x1[cj]);                             \
      }                                                                       \
    }                                                                         \
  }

#define BAR() __builtin_amdgcn_s_barrier()
#define SCHED() __builtin_amdgcn_sched_barrier(0)
#define DRAIN_LGKM()                                                          \
  { asm volatile("s_waitcnt lgkmcnt(0)" ::: "memory"); SCHED(); }

  const int xrow = t >> 2;                 // 0..63
  const int xseg = (t & 3) << 4;           // 0/16/32/48
  const float* xb0 = x + (size_t)(n0 + xrow) * 256 + xseg;
  const float* xb1 = xb0 + 64 * 256;
  float4 xr[8];

#define LOAD_X(KC)                                                            \
  {                                                                           \
    _Pragma("unroll")                                                         \
    for (int j = 0; j < 4; ++j) xr[j]     = *(const float4*)(xb0 + (KC) * 64 + j * 4); \
    _Pragma("unroll")                                                         \
    for (int j = 0; j < 4; ++j) xr[4 + j] = *(const float4*)(xb1 + (KC) * 64 + j * 4); \
  }

#define CVT_AX()                                                              \
  {                                                                           \
    _Pragma("unroll")                                                         \
    for (int hf = 0; hf < 2; ++hf) {                                          \
      u16x8 hv0, hv1, lv0, lv1;                                               \
      _Pragma("unroll")                                                       \
      for (int j = 0; j < 2; ++j) {                                           \
        float f4[8] = {xr[hf*4 + j*2].x, xr[hf*4 + j*2].y, xr[hf*4 + j*2].z,  \
                       xr[hf*4 + j*2].w, xr[hf*4 + j*2 + 1].x,                \
                       xr[hf*4 + j*2 + 1].y, xr[hf*4 + j*2 + 1].z,            \
                       xr[hf*4 + j*2 + 1].w};                                 \
        _Pragma("unroll")                                                     \
        for (int e = 0; e < 8; ++e) {                                         \
          ushort_t hi = f2bf(f4[e]);                                          \
          if (j == 0) { hv0[e] = hi; lv0[e] = f2bf(f4[e] - bf2f(hi)); }       \
          else        { hv1[e] = hi; lv1[e] = f2bf(f4[e] - bf2f(hi)); }       \
        }                                                                     \
      }                                                                       \
      int ro = hf * 64 + xrow;                                                \
      *(u16x8*)&Axh[ro * 72 + xseg]     = hv0;                                \
      *(u16x8*)&Axh[ro * 72 + xseg + 8] = hv1;                                \
      *(u16x8*)&Axl[ro * 72 + xseg]     = lv0;                                \
      *(u16x8*)&Axl[ro * 72 + xseg + 8] = lv1;                                \
    }                                                                         \
  }

#define SOFTMAX(ACC, ROFF)                                                    \
  {                                                                           \
    float cbv[8];                                                             \
    _Pragma("unroll")                                                         \
    for (int cj = 0; cj < 8; ++cj) cbv[cj] = cb_lds[cj * 16 + lr];            \
    _Pragma("unroll")                                                         \
    for (int r = 0; r < 4; ++r) {                                             \
      float v[8];                                                             \
      float m = -1e30f;                                                       \
      _Pragma("unroll")                                                       \
      for (int cj = 0; cj < 8; ++cj) {                                        \
        v[cj] = 2.f * (ACC)[cj][r] + cbv[cj];                                 \
        m = fmaxf(m, v[cj]);                                                  \
      }                                                                       \
      m = fmaxf(m, __shfl_xor(m, 1, 64));                                     \
      m = fmaxf(m, __shfl_xor(m, 2, 64));                                     \
      m = fmaxf(m, __shfl_xor(m, 4, 64));                                     \
      m = fmaxf(m, __shfl_xor(m, 8, 64));                                     \
      float s = 0.f;                                                          \
      _Pragma("unroll")                                                       \
      for (int cj = 0; cj < 8; ++cj) {                                        \
        v[cj] = __expf(v[cj] - m);                                            \
        s += v[cj];                                                           \
      }                                                                       \
      s += __shfl_xor(s, 1, 64);                                              \
      s += __shfl_xor(s, 2, 64);                                              \
      s += __shfl_xor(s, 4, 64);                                              \
      s += __shfl_xor(s, 8, 64);                                              \
      float inv = 1.f / s;                                                    \
      int row = (ROFF) + w * 16 + lk * 4 + r;                                 \
      _Pragma("unroll")                                                       \
      for (int cj = 0; cj < 8; ++cj)                                          \
        A2[row * 136 + cj * 16 + lr] = f2bf(v[cj] * inv);                     \
    }                                                                         \
  }

  // ---- prologue ----
  cb_lds[t & 127] = cbias[h * 128 + (t & 127)];
  LOAD_X(0);
  STAGE_BX(B0lds, 0);
  SCHED();                                 // pin B0 before B1 (vmcnt counting)
  STAGE_BX(B1lds, 1);
  SCHED();
  f32x4 acc_x0[4], acc_x1[4];
  #pragma unroll
  for (int cj = 0; cj < 4; ++cj) {
    acc_x0[cj] = (f32x4){0.f, 0.f, 0.f, 0.f};
    acc_x1[cj] = (f32x4){0.f, 0.f, 0.f, 0.f};
  }
  CVT_AX();                                // consume x0 (leaves B0,B1)
  SCHED();
  LOAD_X(1);                               // Q: [B0:4, B1:4, x1:8]
  asm volatile("s_waitcnt vmcnt(12)" ::: "memory");  // B0 done
  DRAIN_LGKM(); BAR(); SCHED();
  // chunk 0
  MFMAX(B0lds);
  DRAIN_LGKM(); BAR(); SCHED();
  STAGE_BX(B0lds, 2);                      // Q: [B1, x1, B2]
  SCHED();
  CVT_AX();                                // consume x1 -> forces B1 done
  SCHED();
  LOAD_X(2);                               // Q: [B2:4, x2:8]
  DRAIN_LGKM(); BAR(); SCHED();
  // chunk 1
  MFMAX(B1lds);
  DRAIN_LGKM(); BAR(); SCHED();
  STAGE_BX(B1lds, 3);                      // Q: [B2, x2, B3]
  SCHED();
  CVT_AX();                                // consume x2 -> forces B2 done
  SCHED();
  LOAD_X(3);                               // Q: [B3:4, x3:8]
  DRAIN_LGKM(); BAR(); SCHED();
  // chunk 2
  MFMAX(B0lds);
  DRAIN_LGKM(); BAR(); SCHED();
  STAGE_B(B0lds, ctr3T, 192, 0);           // Q: [B3, x3, ctr0]
  SCHED();
  CVT_AX();                                // consume x3 -> forces B3 done
  DRAIN_LGKM(); BAR(); SCHED();
  // chunk 3
  MFMAX(B1lds);
  DRAIN_LGKM(); BAR(); SCHED();            // B1lds, Ax free

  // write A1 (xin hi|lo) from acc_x — own wave's rows (Ax now dead)
  STAGE_B(B1lds, ctr3T, 192, 64);          // Q: [ctr0:4, ctr64:4]
  #pragma unroll
  for (int cj = 0; cj < 4; ++cj) {
    #pragma unroll
    for (int r = 0; r < 4; ++r) {
      int row = w * 16 + lk * 4 + r;
      int p = cj * 16 + lr;
      float v0 = acc_x0[cj][r];
      ushort_t hi0 = f2bf(v0);
      A1[row * 136 + p] = hi0;
      A1[row * 136 + 64 + p] = f2bf(v0 - bf2f(hi0));
      float v1 = acc_x1[cj][r];
      ushort_t hi1 = f2bf(v1);
      A1[(64 + row) * 136 + p] = hi1;
      A1[(64 + row) * 136 + 64 + p] = f2bf(v1 - bf2f(hi1));
    }
  }
  asm volatile("s_waitcnt vmcnt(4)" ::: "memory");  // ctr0 done
  DRAIN_LGKM(); BAR(); SCHED();

  // ---- logits: K=192 ----
  f32x4 acc0[8], acc1[8];
  #pragma unroll
  for (int cj = 0; cj < 8; ++cj) {
    acc0[cj] = (f32x4){0.f, 0.f, 0.f, 0.f};
    acc1[cj] = (f32x4){0.f, 0.f, 0.f, 0.f};
  }
  MFMA_STEP(B0lds, acc0, acc1, 0, 1);      // L0
  DRAIN_LGKM(); BAR(); SCHED();
  STAGE_B(B0lds, ctr3T, 192, 128);         // Q: [ctr64, ctr128]
  asm volatile("s_waitcnt vmcnt(4)" ::: "memory");
  BAR(); SCHED();
  MFMA_STEP(B1lds, acc0, acc1, 64, 1);     // L1
  DRAIN_LGKM(); BAR(); SCHED();
  STAGE_B(B1lds, W2bT, 128, 0);            // Q: [ctr128, W2k0]
  asm volatile("s_waitcnt vmcnt(4)" ::: "memory");
  BAR(); SCHED();
  MFMA_STEP(B0lds, acc0, acc1, 128, 1);    // L2
  DRAIN_LGKM();                            // A1 reads landed

  // ---- softmax (rows within wave; A2 overwrites A1 at own-wave rows) ----
  SOFTMAX(acc0, 0);
  SOFTMAX(acc1, 64);
  DRAIN_LGKM();
  BAR(); SCHED();        // safe to overwrite B0lds

  f32x4 accT0[8], accT1[8];
  #pragma unroll
  for (int cj = 0; cj < 8; ++cj) {
    accT0[cj] = (f32x4){0.f, 0.f, 0.f, 0.f};
    accT1[cj] = (f32x4){0.f, 0.f, 0.f, 0.f};
  }
  STAGE_B(B0lds, W2bT, 128, 64);           // Q: [W2k0, W2k64]
  asm volatile("s_waitcnt vmcnt(4)" ::: "memory");
  BAR(); SCHED();
  { // T0 reads B1lds; A-operand = A2 (same union address as A1)
    MFMA_STEP(B1lds, accT0, accT1, 0, 0);
  }
  DRAIN_LGKM();
  asm volatile("s_waitcnt vmcnt(0)" ::: "memory");
  BAR(); SCHED();
  MFMA_STEP(B0lds, accT0, accT1, 64, 0);   // T1

  // ---- epilogue: ho = xin(f32 regs)*t1 + t2 ; bounce both tiles via B1lds --
  #pragma unroll
  for (int cj = 0; cj < 4; ++cj) {
    #pragma unroll
    for (int r = 0; r < 4; ++r) {
      int row = w * 16 + lk * 4 + r;
      int p = cj * 16 + lr;
      float hov0 = acc_x0[cj][r] * accT0[cj][r] + accT0[cj + 4][r];
      ((ushort_t*)B1lds)[row * 64 + p] = f2bf(hov0);
      float hov1 = acc_x1[cj][r] * accT1[cj][r] + accT1[cj + 4][r];
      ((ushort_t*)B1lds)[(64 + row) * 64 + p] = f2bf(hov1);
    }
  }
  DRAIN_LGKM(); BAR(); SCHED();
  #pragma unroll
  for (int i = 0; i < 4; ++i) {
    int q = i * 256 + t;
    int row = q >> 3, s = q & 7;
    uint4 v = *(const uint4*)((const char*)B1lds + row * 128 + s * 16);
    *(uint4*)(ho2 + ((size_t)h * NROWS + n0 + row) * 64 + s * 8) = v;
  }
#undef STAGE_B
#undef STAGE_BX
#undef MFMA_STEP
#undef MFMAX
#undef BAR
#undef SCHED
#undef DRAIN_LGKM
#undef LOAD_X
#undef CVT_AX
#undef SOFTMAX
}

// ---------------------------------------------------------------------------
extern "C" void kernel_launch(void* const* d_in, const int* in_sizes, int n_in,
                              void* d_out, int out_size, void* d_ws, size_t ws_size,
                              hipStream_t stream) {
  (void)in_sizes; (void)n_in; (void)out_size; (void)ws_size;
  const float* x    = (const float*)d_in[0];
  const float* ctrs = (const float*)d_in[1];
  const float* Wv   = (const float*)d_in[2];
  const float* Ov   = (const float*)d_in[3];
  const float* Wq   = (const float*)d_in[4];
  const float* Wo   = (const float*)d_in[5];
  float* out = (float*)d_out;

  char* wsb = (char*)d_ws;
  ushort_t* wcvtT = (ushort_t*)wsb;                   // [0, 524288)
  ushort_t* ctr3T = (ushort_t*)(wsb + 524288);        // [524288, 917504)
  float*    cb    = (float*)   (wsb + 917504);        // [917504, 921600)
  ushort_t* W2bT  = (ushort_t*)(wsb + 921600);        // [921600, 1183744)
  ushort_t* WoT   = (ushort_t*)(wsb + 1183744);       // [1183744, 1445888)
  ushort_t* ho2   = (ushort_t*)(wsb + 2097152);       // [2 MiB, 2 MiB + 8 MiB)

  prep_kernel<<<1536, 256, 0, stream>>>(Wq, ctrs, Wo, Wv, Ov,
                                        wcvtT, ctr3T, cb, WoT, W2bT);
  fused_pair_kernel<<<512, 256, 0, stream>>>(x, wcvtT, ctr3T, cb, W2bT, ho2);
  gemm2_kernel<<<512, 256, 0, stream>>>(ho2, WoT, out);
}